// Round 3
// baseline (123.024 us; speedup 1.0000x reference)
//
#include <hip/hip_runtime.h>
#include <math.h>

#define HH 1024
#define WW 1024
#define RR 8192
#define EPSF 1e-10f
#define EPSD 1e-10

// ws layout (bytes):
//   [0,          8388608)  rowpref -> becomes integral image C in-place (1024*1024 f64)
//   [8388608,    8650752)  bsum (32*1024 f64) column chunk sums
//   [8650752,    8683520)  iou (8192 f32)
//   [8683520,    8683560)  stats: 5 f64  {Su, Su2, Ss, Ss2, Sab}
//   [8683560,    8683564)  cnt: 1 u32 completion counter for pair_prod
#define OFF_BSUM  8388608
#define OFF_IOU   8650752
#define OFF_STAT  8683520
#define OFF_CNT   8683560

__device__ __forceinline__ double sigm(float a, float b) {
    // softmax over 2 channels, channel 1: 1/(1+exp(a-b)); fp32 fast path
    float z = (a - b) * 1.44269504088896f;          // log2(e)
    float e = __builtin_amdgcn_exp2f(z);            // v_exp_f32
    float sg = __builtin_amdgcn_rcpf(1.0f + e);     // v_rcp_f32
    return (double)sg;
}

// Kernel A: per-row prefix sum of sigmoid(seg1-seg0), fp64 out. One block per row.
__global__ void row_scan(const float* __restrict__ seg, double* __restrict__ rowpref) {
    const int h = blockIdx.x;
    const int t = threadIdx.x;
    const float4* s0 = (const float4*)(seg + (size_t)h * WW);
    const float4* s1 = (const float4*)(seg + (size_t)(HH * WW) + (size_t)h * WW);
    float4 a = s0[t];
    float4 b = s1[t];
    double p0 = sigm(a.x, b.x);
    double p1 = p0 + sigm(a.y, b.y);
    double p2 = p1 + sigm(a.z, b.z);
    double p3 = p2 + sigm(a.w, b.w);

    double tsum = p3;
    const int lane = t & 63, wid = t >> 6;
    #pragma unroll
    for (int off = 1; off < 64; off <<= 1) {
        double n = __shfl_up(tsum, off, 64);
        if (lane >= off) tsum += n;
    }
    __shared__ double wsum[4];
    if (lane == 63) wsum[wid] = tsum;
    __syncthreads();
    double woff = 0.0;
    for (int k = 0; k < wid; ++k) woff += wsum[k];
    const double excl = woff + tsum - p3;

    double* out = rowpref + (size_t)h * WW + 4 * t;
    out[0] = excl + p0;
    out[1] = excl + p1;
    out[2] = excl + p2;
    out[3] = excl + p3;
}

// Kernel B: per-(32-row chunk, column) partial sums. grid (4, 32), block 256.
// Block (0,0) also zero-inits the stats accumulators + completion counter.
__global__ void col_partial(const double* __restrict__ rowpref, double* __restrict__ bsum,
                            double* __restrict__ stats, unsigned* __restrict__ cnt) {
    if (blockIdx.x == 0 && blockIdx.y == 0) {
        if (threadIdx.x < 5) stats[threadIdx.x] = 0.0;
        if (threadIdx.x == 5) *cnt = 0u;
    }
    const int w = blockIdx.x * 256 + threadIdx.x;
    const int chunk = blockIdx.y;
    const int r0 = chunk * 32;
    double acc = 0.0;
    #pragma unroll 4
    for (int r = r0; r < r0 + 32; ++r) acc += rowpref[(size_t)r * WW + w];
    bsum[chunk * WW + w] = acc;
}

// Kernel C: column scan; rowpref becomes the integral image in place.
__global__ void col_scan(double* __restrict__ rowpref, const double* __restrict__ bsum) {
    const int w = blockIdx.x * 256 + threadIdx.x;
    const int chunk = blockIdx.y;
    double acc = 0.0;
    for (int k = 0; k < chunk; ++k) acc += bsum[k * WW + w];
    const int r0 = chunk * 32;
    for (int r = r0; r < r0 + 32; ++r) {
        acc += rowpref[(size_t)r * WW + w];
        rowpref[(size_t)r * WW + w] = acc;
    }
}

// Kernel D: per-box iou + fp64 reductions of {Σu, Σu², Σs, Σs²}.
__global__ void box_stats(const int* __restrict__ ssw, const double* __restrict__ C,
                          const float* __restrict__ score,
                          float* __restrict__ iou, double* __restrict__ stats) {
    const int r = blockIdx.x * 256 + threadIdx.x;
    const int* b = ssw + r * 5;
    const int x1 = b[1], y1 = b[2], x2 = b[3], y2 = b[4];
    double p22 = C[(size_t)(y2 - 1) * WW + (x2 - 1)];
    double p12 = (y1 > 0) ? C[(size_t)(y1 - 1) * WW + (x2 - 1)] : 0.0;
    double p21 = (x1 > 0) ? C[(size_t)(y2 - 1) * WW + (x1 - 1)] : 0.0;
    double p11 = (y1 > 0 && x1 > 0) ? C[(size_t)(y1 - 1) * WW + (x1 - 1)] : 0.0;
    double sums = p22 - p12 - p21 + p11;
    double area = (double)((y2 - y1) * (x2 - x1));
    double u = sums / area;
    iou[r] = (float)u;
    double s = (double)score[r];

    double v0 = u, v1 = u * u, v2 = s, v3 = s * s;
    #pragma unroll
    for (int off = 32; off; off >>= 1) {
        v0 += __shfl_down(v0, off, 64);
        v1 += __shfl_down(v1, off, 64);
        v2 += __shfl_down(v2, off, 64);
        v3 += __shfl_down(v3, off, 64);
    }
    if ((threadIdx.x & 63) == 0) {
        atomicAdd(&stats[0], v0);
        atomicAdd(&stats[1], v1);
        atomicAdd(&stats[2], v2);
        atomicAdd(&stats[3], v3);
    }
}

// Kernel E: S_ab = Σ_ij sqrt((du²+ε)(ds²+ε)), fused finalize via completion counter.
// Grid (8192/(256*8), 8192/32) = (4, 256) = 1024 blocks, block 256, 8 i per thread.
#define KI 8
#define JT 32
#define NBLK ((RR / (256 * KI)) * (RR / JT))
__global__ void pair_prod(const float* __restrict__ iou, const float* __restrict__ score,
                          double* __restrict__ stats, unsigned* __restrict__ cnt,
                          float* __restrict__ out) {
    __shared__ float ju[JT];
    __shared__ float js[JT];
    const int t = threadIdx.x;
    const int j0 = blockIdx.y * JT;
    if (t < JT) {
        ju[t] = iou[j0 + t];
        js[t] = score[j0 + t];
    }
    const int i0 = blockIdx.x * (256 * KI) + t;
    float iu[KI], isc[KI];
    #pragma unroll
    for (int k = 0; k < KI; ++k) {
        iu[k]  = iou[i0 + 256 * k];
        isc[k] = score[i0 + 256 * k];
    }
    __syncthreads();

    float acc[KI];
    #pragma unroll
    for (int k = 0; k < KI; ++k) acc[k] = 0.0f;
    #pragma unroll 4
    for (int j = 0; j < JT; ++j) {
        const float uj = ju[j];
        const float sj = js[j];
        #pragma unroll
        for (int k = 0; k < KI; ++k) {
            float du = iu[k] - uj;
            float p  = fmaf(du, du, EPSF);
            float ds = isc[k] - sj;
            float q  = fmaf(ds, ds, EPSF);
            acc[k] += __builtin_amdgcn_sqrtf(p * q);
        }
    }
    float afl = 0.0f;
    #pragma unroll
    for (int k = 0; k < KI; ++k) afl += acc[k];
    double v = (double)afl;
    #pragma unroll
    for (int off = 32; off; off >>= 1) v += __shfl_down(v, off, 64);
    __shared__ double wred[4];
    const int lane = t & 63, wid = t >> 6;
    if (lane == 0) wred[wid] = v;
    __syncthreads();
    if (t == 0) {
        atomicAdd(&stats[4], wred[0] + wred[1] + wred[2] + wred[3]);
        __threadfence();
        unsigned old = atomicAdd(cnt, 1u);
        if (old == NBLK - 1) {
            // last block: all stats visible (each block fenced before incrementing)
            const double R = (double)RR;
            double Su = stats[0], Su2 = stats[1], Ss = stats[2], Ss2 = stats[3], Sab = stats[4];
            double lossR2 = 2.0 * R * Su2 - 2.0 * Su * Su
                          + 2.0 * R * Ss2 - 2.0 * Ss * Ss
                          + 2.0 * R * R * EPSD
                          - 2.0 * Sab;
            out[0] = (float)(lossR2 / (R * R));
        }
    }
}

extern "C" void kernel_launch(void* const* d_in, const int* in_sizes, int n_in,
                              void* d_out, int out_size, void* d_ws, size_t ws_size,
                              hipStream_t stream) {
    const int*   ssw   = (const int*)d_in[0];
    const float* seg   = (const float*)d_in[1];
    const float* score = (const float*)d_in[2];

    double*   rowpref = (double*)d_ws;
    double*   bsum    = (double*)((char*)d_ws + OFF_BSUM);
    float*    iou     = (float*)((char*)d_ws + OFF_IOU);
    double*   stats   = (double*)((char*)d_ws + OFF_STAT);
    unsigned* cnt     = (unsigned*)((char*)d_ws + OFF_CNT);

    row_scan<<<HH, 256, 0, stream>>>(seg, rowpref);
    col_partial<<<dim3(4, 32), 256, 0, stream>>>(rowpref, bsum, stats, cnt);
    col_scan<<<dim3(4, 32), 256, 0, stream>>>(rowpref, bsum);
    box_stats<<<RR / 256, 256, 0, stream>>>(ssw, rowpref, score, iou, stats);
    pair_prod<<<dim3(RR / (256 * KI), RR / JT), 256, 0, stream>>>(iou, score, stats, cnt, (float*)d_out);
}

// Round 4
// 118.772 us; speedup vs baseline: 1.0358x; 1.0358x over previous
//
#include <hip/hip_runtime.h>
#include <math.h>

#define HH 1024
#define WW 1024
#define RR 8192
#define EPSF 1e-10f
#define EPSD 1e-10

// ws layout (bytes):
//   [0,          8388608)  rowpref -> becomes integral image C in-place (1024*1024 f64)
//   [8388608,    8912896)  bsum (64*1024 f64) column chunk sums (16-row chunks)
//   [8912896,    8945664)  iou (8192 f32)
//   [8945664,    8945704)  stats: 5 f64  {Su, Su2, Ss, Ss2, Sab}
//   [8945704,    8945708)  cnt: 1 u32 completion counter for pair_prod
#define OFF_BSUM  8388608
#define OFF_IOU   8912896
#define OFF_STAT  8945664
#define OFF_CNT   8945704

__device__ __forceinline__ double sigm(float a, float b) {
    // softmax over 2 channels, channel 1: 1/(1+exp(a-b)); fp32 fast path
    float z = (a - b) * 1.44269504088896f;          // log2(e)
    float e = __builtin_amdgcn_exp2f(z);            // v_exp_f32
    float sg = __builtin_amdgcn_rcpf(1.0f + e);     // v_rcp_f32
    return (double)sg;
}

// Kernel A: per-row prefix sum of sigmoid(seg1-seg0), fp64 out. One block per row.
// Block 0 also zero-inits the stats accumulators + completion counter.
__global__ void row_scan(const float* __restrict__ seg, double* __restrict__ rowpref,
                         double* __restrict__ stats, unsigned* __restrict__ cnt) {
    if (blockIdx.x == 0) {
        if (threadIdx.x < 5) stats[threadIdx.x] = 0.0;
        if (threadIdx.x == 5) *cnt = 0u;
    }
    const int h = blockIdx.x;
    const int t = threadIdx.x;
    const float4* s0 = (const float4*)(seg + (size_t)h * WW);
    const float4* s1 = (const float4*)(seg + (size_t)(HH * WW) + (size_t)h * WW);
    float4 a = s0[t];
    float4 b = s1[t];
    double p0 = sigm(a.x, b.x);
    double p1 = p0 + sigm(a.y, b.y);
    double p2 = p1 + sigm(a.z, b.z);
    double p3 = p2 + sigm(a.w, b.w);

    double tsum = p3;
    const int lane = t & 63, wid = t >> 6;
    #pragma unroll
    for (int off = 1; off < 64; off <<= 1) {
        double n = __shfl_up(tsum, off, 64);
        if (lane >= off) tsum += n;
    }
    __shared__ double wsum[4];
    if (lane == 63) wsum[wid] = tsum;
    __syncthreads();
    double woff = 0.0;
    for (int k = 0; k < wid; ++k) woff += wsum[k];
    const double excl = woff + tsum - p3;

    double* out = rowpref + (size_t)h * WW + 4 * t;
    out[0] = excl + p0;
    out[1] = excl + p1;
    out[2] = excl + p2;
    out[3] = excl + p3;
}

// Kernel B: per-(16-row chunk, column) partial sums. grid (4, 64), block 256.
__global__ void col_partial(const double* __restrict__ rowpref, double* __restrict__ bsum) {
    const int w = blockIdx.x * 256 + threadIdx.x;
    const int chunk = blockIdx.y;
    const int r0 = chunk * 16;
    double acc = 0.0;
    #pragma unroll
    for (int r = r0; r < r0 + 16; ++r) acc += rowpref[(size_t)r * WW + w];
    bsum[chunk * WW + w] = acc;
}

// Kernel C: column scan; rowpref becomes the integral image in place. grid (4, 64).
__global__ void col_scan(double* __restrict__ rowpref, const double* __restrict__ bsum) {
    const int w = blockIdx.x * 256 + threadIdx.x;
    const int chunk = blockIdx.y;
    double acc = 0.0;
    for (int k = 0; k < chunk; ++k) acc += bsum[k * WW + w];
    const int r0 = chunk * 16;
    #pragma unroll
    for (int r = r0; r < r0 + 16; ++r) {
        acc += rowpref[(size_t)r * WW + w];
        rowpref[(size_t)r * WW + w] = acc;
    }
}

// Kernel D: per-box iou + fp64 reductions of {Σu, Σu², Σs, Σs²}.
__global__ void box_stats(const int* __restrict__ ssw, const double* __restrict__ C,
                          const float* __restrict__ score,
                          float* __restrict__ iou, double* __restrict__ stats) {
    const int r = blockIdx.x * 256 + threadIdx.x;
    const int* b = ssw + r * 5;
    const int x1 = b[1], y1 = b[2], x2 = b[3], y2 = b[4];
    double p22 = C[(size_t)(y2 - 1) * WW + (x2 - 1)];
    double p12 = (y1 > 0) ? C[(size_t)(y1 - 1) * WW + (x2 - 1)] : 0.0;
    double p21 = (x1 > 0) ? C[(size_t)(y2 - 1) * WW + (x1 - 1)] : 0.0;
    double p11 = (y1 > 0 && x1 > 0) ? C[(size_t)(y1 - 1) * WW + (x1 - 1)] : 0.0;
    double sums = p22 - p12 - p21 + p11;
    double area = (double)((y2 - y1) * (x2 - x1));
    double u = sums / area;
    iou[r] = (float)u;
    double s = (double)score[r];

    double v0 = u, v1 = u * u, v2 = s, v3 = s * s;
    #pragma unroll
    for (int off = 32; off; off >>= 1) {
        v0 += __shfl_down(v0, off, 64);
        v1 += __shfl_down(v1, off, 64);
        v2 += __shfl_down(v2, off, 64);
        v3 += __shfl_down(v3, off, 64);
    }
    if ((threadIdx.x & 63) == 0) {
        atomicAdd(&stats[0], v0);
        atomicAdd(&stats[1], v1);
        atomicAdd(&stats[2], v2);
        atomicAdd(&stats[3], v3);
    }
}

// Kernel E: S_ab = Σ_ij sqrt((du²+ε)(ds²+ε)), fused finalize via completion counter.
// Grid (8192/1024, 8192/128) = (8, 64) = 512 blocks, block 256, 4 i per thread.
#define KI 4
#define JT 128
#define NBLK ((RR / (256 * KI)) * (RR / JT))
__global__ void pair_prod(const float* __restrict__ iou, const float* __restrict__ score,
                          double* __restrict__ stats, unsigned* __restrict__ cnt,
                          float* __restrict__ out) {
    __shared__ float ju[JT];
    __shared__ float js[JT];
    const int t = threadIdx.x;
    const int j0 = blockIdx.y * JT;
    if (t < JT) ju[t] = iou[j0 + t];
    else js[t - JT] = score[j0 + t - JT];

    const int i0 = blockIdx.x * (256 * KI) + t;
    float iu[KI], isc[KI];
    #pragma unroll
    for (int k = 0; k < KI; ++k) {
        iu[k]  = iou[i0 + 256 * k];
        isc[k] = score[i0 + 256 * k];
    }
    __syncthreads();

    float acc[KI];
    #pragma unroll
    for (int k = 0; k < KI; ++k) acc[k] = 0.0f;
    #pragma unroll 8
    for (int j = 0; j < JT; ++j) {
        const float uj = ju[j];
        const float sj = js[j];
        #pragma unroll
        for (int k = 0; k < KI; ++k) {
            float du = iu[k] - uj;
            float p  = fmaf(du, du, EPSF);
            float ds = isc[k] - sj;
            float q  = fmaf(ds, ds, EPSF);
            acc[k] += __builtin_amdgcn_sqrtf(p * q);
        }
    }
    float afl = (acc[0] + acc[1]) + (acc[2] + acc[3]);
    double v = (double)afl;
    #pragma unroll
    for (int off = 32; off; off >>= 1) v += __shfl_down(v, off, 64);
    __shared__ double wred[4];
    const int lane = t & 63, wid = t >> 6;
    if (lane == 0) wred[wid] = v;
    __syncthreads();
    if (t == 0) {
        atomicAdd(&stats[4], wred[0] + wred[1] + wred[2] + wred[3]);
        __threadfence();
        unsigned old = atomicAdd(cnt, 1u);
        if (old == NBLK - 1) {
            // last block: read stats via atomic RMW (coherent point, no stale L1/L2)
            double Su  = atomicAdd(&stats[0], 0.0);
            double Su2 = atomicAdd(&stats[1], 0.0);
            double Ss  = atomicAdd(&stats[2], 0.0);
            double Ss2 = atomicAdd(&stats[3], 0.0);
            double Sab = atomicAdd(&stats[4], 0.0);
            const double R = (double)RR;
            double lossR2 = 2.0 * R * Su2 - 2.0 * Su * Su
                          + 2.0 * R * Ss2 - 2.0 * Ss * Ss
                          + 2.0 * R * R * EPSD
                          - 2.0 * Sab;
            out[0] = (float)(lossR2 / (R * R));
        }
    }
}

extern "C" void kernel_launch(void* const* d_in, const int* in_sizes, int n_in,
                              void* d_out, int out_size, void* d_ws, size_t ws_size,
                              hipStream_t stream) {
    const int*   ssw   = (const int*)d_in[0];
    const float* seg   = (const float*)d_in[1];
    const float* score = (const float*)d_in[2];

    double*   rowpref = (double*)d_ws;
    double*   bsum    = (double*)((char*)d_ws + OFF_BSUM);
    float*    iou     = (float*)((char*)d_ws + OFF_IOU);
    double*   stats   = (double*)((char*)d_ws + OFF_STAT);
    unsigned* cnt     = (unsigned*)((char*)d_ws + OFF_CNT);

    row_scan<<<HH, 256, 0, stream>>>(seg, rowpref, stats, cnt);
    col_partial<<<dim3(4, 64), 256, 0, stream>>>(rowpref, bsum);
    col_scan<<<dim3(4, 64), 256, 0, stream>>>(rowpref, bsum);
    box_stats<<<RR / 256, 256, 0, stream>>>(ssw, rowpref, score, iou, stats);
    pair_prod<<<dim3(RR / (256 * KI), RR / JT), 256, 0, stream>>>(iou, score, stats, cnt, (float*)d_out);
}

// Round 5
// 111.999 us; speedup vs baseline: 1.0984x; 1.0605x over previous
//
#include <hip/hip_runtime.h>
#include <math.h>

#define HH 1024
#define WW 1024
#define RR 8192
#define EPSD 1e-10

// ws layout (bytes):
//   [0,          8388608)  rowpref -> becomes integral image C in-place (1024*1024 f64)
//   [8388608,    8912896)  bsum (64*1024 f64) column chunk sums (16-row chunks)
//   [8912896,    8945664)  iou (8192 f32)
//   [8945664,    8945704)  stats: 5 f64  {Su, Su2, Ss, Ss2, Sab}
#define OFF_BSUM  8388608
#define OFF_IOU   8912896
#define OFF_STAT  8945664

__device__ __forceinline__ double sigm(float a, float b) {
    // softmax over 2 channels, channel 1: 1/(1+exp(a-b)); fp32 fast path
    float z = (a - b) * 1.44269504088896f;          // log2(e)
    float e = __builtin_amdgcn_exp2f(z);            // v_exp_f32
    float sg = __builtin_amdgcn_rcpf(1.0f + e);     // v_rcp_f32
    return (double)sg;
}

// Kernel A: per-row prefix sum of sigmoid(seg1-seg0), fp64 out. One block per row.
// Block 0 also zero-inits the stats accumulators.
__global__ void row_scan(const float* __restrict__ seg, double* __restrict__ rowpref,
                         double* __restrict__ stats) {
    if (blockIdx.x == 0 && threadIdx.x < 5) stats[threadIdx.x] = 0.0;
    const int h = blockIdx.x;
    const int t = threadIdx.x;
    const float4* s0 = (const float4*)(seg + (size_t)h * WW);
    const float4* s1 = (const float4*)(seg + (size_t)(HH * WW) + (size_t)h * WW);
    float4 a = s0[t];
    float4 b = s1[t];
    double p0 = sigm(a.x, b.x);
    double p1 = p0 + sigm(a.y, b.y);
    double p2 = p1 + sigm(a.z, b.z);
    double p3 = p2 + sigm(a.w, b.w);

    double tsum = p3;
    const int lane = t & 63, wid = t >> 6;
    #pragma unroll
    for (int off = 1; off < 64; off <<= 1) {
        double n = __shfl_up(tsum, off, 64);
        if (lane >= off) tsum += n;
    }
    __shared__ double wsum[4];
    if (lane == 63) wsum[wid] = tsum;
    __syncthreads();
    double woff = 0.0;
    for (int k = 0; k < wid; ++k) woff += wsum[k];
    const double excl = woff + tsum - p3;

    double* out = rowpref + (size_t)h * WW + 4 * t;
    out[0] = excl + p0;
    out[1] = excl + p1;
    out[2] = excl + p2;
    out[3] = excl + p3;
}

// Kernel B: per-(16-row chunk, column) partial sums. grid (4, 64), block 256.
__global__ void col_partial(const double* __restrict__ rowpref, double* __restrict__ bsum) {
    const int w = blockIdx.x * 256 + threadIdx.x;
    const int chunk = blockIdx.y;
    const int r0 = chunk * 16;
    double acc = 0.0;
    #pragma unroll
    for (int r = r0; r < r0 + 16; ++r) acc += rowpref[(size_t)r * WW + w];
    bsum[chunk * WW + w] = acc;
}

// Kernel C: column scan; rowpref becomes the integral image in place. grid (4, 64).
__global__ void col_scan(double* __restrict__ rowpref, const double* __restrict__ bsum) {
    const int w = blockIdx.x * 256 + threadIdx.x;
    const int chunk = blockIdx.y;
    double acc = 0.0;
    for (int k = 0; k < chunk; ++k) acc += bsum[k * WW + w];
    const int r0 = chunk * 16;
    #pragma unroll
    for (int r = r0; r < r0 + 16; ++r) {
        acc += rowpref[(size_t)r * WW + w];
        rowpref[(size_t)r * WW + w] = acc;
    }
}

// Kernel D: per-box iou + fp64 reductions of {Σu, Σu², Σs, Σs²}.
__global__ void box_stats(const int* __restrict__ ssw, const double* __restrict__ C,
                          const float* __restrict__ score,
                          float* __restrict__ iou, double* __restrict__ stats) {
    const int r = blockIdx.x * 256 + threadIdx.x;
    const int* b = ssw + r * 5;
    const int x1 = b[1], y1 = b[2], x2 = b[3], y2 = b[4];
    double p22 = C[(size_t)(y2 - 1) * WW + (x2 - 1)];
    double p12 = (y1 > 0) ? C[(size_t)(y1 - 1) * WW + (x2 - 1)] : 0.0;
    double p21 = (x1 > 0) ? C[(size_t)(y2 - 1) * WW + (x1 - 1)] : 0.0;
    double p11 = (y1 > 0 && x1 > 0) ? C[(size_t)(y1 - 1) * WW + (x1 - 1)] : 0.0;
    double sums = p22 - p12 - p21 + p11;
    double area = (double)((y2 - y1) * (x2 - x1));
    double u = sums / area;
    iou[r] = (float)u;
    double s = (double)score[r];

    double v0 = u, v1 = u * u, v2 = s, v3 = s * s;
    #pragma unroll
    for (int off = 32; off; off >>= 1) {
        v0 += __shfl_down(v0, off, 64);
        v1 += __shfl_down(v1, off, 64);
        v2 += __shfl_down(v2, off, 64);
        v3 += __shfl_down(v3, off, 64);
    }
    if ((threadIdx.x & 63) == 0) {
        atomicAdd(&stats[0], v0);
        atomicAdd(&stats[1], v1);
        atomicAdd(&stats[2], v2);
        atomicAdd(&stats[3], v3);
    }
}

// Kernel E: S_ab = Σ_ij |du|·|ds|  (≈ Σ sqrt((du²+ε)(ds²+ε)), error < 1e-7 in loss).
// Grid (8192/1024, 8192/128) = (8, 64) = 512 blocks, block 256, 4 i per thread.
#define KI 4
#define JT 128
__global__ void pair_prod(const float* __restrict__ iou, const float* __restrict__ score,
                          double* __restrict__ stats) {
    __shared__ float ju[JT];
    __shared__ float js[JT];
    const int t = threadIdx.x;
    const int j0 = blockIdx.y * JT;
    if (t < JT) ju[t] = iou[j0 + t];
    else js[t - JT] = score[j0 + t - JT];

    const int i0 = blockIdx.x * (256 * KI) + t;
    float iu[KI], isc[KI];
    #pragma unroll
    for (int k = 0; k < KI; ++k) {
        iu[k]  = iou[i0 + 256 * k];
        isc[k] = score[i0 + 256 * k];
    }
    __syncthreads();

    float acc[KI];
    #pragma unroll
    for (int k = 0; k < KI; ++k) acc[k] = 0.0f;
    #pragma unroll 8
    for (int j = 0; j < JT; ++j) {
        const float uj = ju[j];
        const float sj = js[j];
        #pragma unroll
        for (int k = 0; k < KI; ++k) {
            float du = iu[k] - uj;
            float ds = isc[k] - sj;
            acc[k] += fabsf(du * ds);   // v_mul + v_add with |src| modifier
        }
    }
    float afl = (acc[0] + acc[1]) + (acc[2] + acc[3]);
    double v = (double)afl;
    #pragma unroll
    for (int off = 32; off; off >>= 1) v += __shfl_down(v, off, 64);
    __shared__ double wred[4];
    const int lane = t & 63, wid = t >> 6;
    if (lane == 0) wred[wid] = v;
    __syncthreads();
    if (t == 0) atomicAdd(&stats[4], wred[0] + wred[1] + wred[2] + wred[3]);
}

// Kernel F: loss = [2RΣu² − 2(Σu)² + 2RΣs² − 2(Σs)² + 2R²ε − 2 S_ab] / R²
__global__ void finalize(const double* __restrict__ stats, float* __restrict__ out) {
    const double R = (double)RR;
    double Su = stats[0], Su2 = stats[1], Ss = stats[2], Ss2 = stats[3], Sab = stats[4];
    double lossR2 = 2.0 * R * Su2 - 2.0 * Su * Su
                  + 2.0 * R * Ss2 - 2.0 * Ss * Ss
                  + 2.0 * R * R * EPSD
                  - 2.0 * Sab;
    out[0] = (float)(lossR2 / (R * R));
}

extern "C" void kernel_launch(void* const* d_in, const int* in_sizes, int n_in,
                              void* d_out, int out_size, void* d_ws, size_t ws_size,
                              hipStream_t stream) {
    const int*   ssw   = (const int*)d_in[0];
    const float* seg   = (const float*)d_in[1];
    const float* score = (const float*)d_in[2];

    double* rowpref = (double*)d_ws;
    double* bsum    = (double*)((char*)d_ws + OFF_BSUM);
    float*  iou     = (float*)((char*)d_ws + OFF_IOU);
    double* stats   = (double*)((char*)d_ws + OFF_STAT);

    row_scan<<<HH, 256, 0, stream>>>(seg, rowpref, stats);
    col_partial<<<dim3(4, 64), 256, 0, stream>>>(rowpref, bsum);
    col_scan<<<dim3(4, 64), 256, 0, stream>>>(rowpref, bsum);
    box_stats<<<RR / 256, 256, 0, stream>>>(ssw, rowpref, score, iou, stats);
    pair_prod<<<dim3(RR / (256 * KI), RR / JT), 256, 0, stream>>>(iou, score, stats);
    finalize<<<1, 1, 0, stream>>>(stats, (float*)d_out);
}

// Round 6
// 108.610 us; speedup vs baseline: 1.1327x; 1.0312x over previous
//
#include <hip/hip_runtime.h>
#include <math.h>

#define HH 1024
#define WW 1024
#define RR 8192
#define EPSD 1e-10

// ws layout (bytes):
//   [0,         4194304)  rowpref: fp32 per-row prefix sums (1024*1024 f32)
//   [4194304,  12582912)  C: fp64 integral image (1024*1024 f64)
//   [12582912, 13107200)  bsum (64*1024 f64) column chunk sums (16-row chunks)
//   [13107200, 13139968)  iou (8192 f32)
//   [13139968, 13140008)  stats: 5 f64  {Su, Su2, Ss, Ss2, Sab}
#define OFF_C     4194304
#define OFF_BSUM  12582912
#define OFF_IOU   13107200
#define OFF_STAT  13139968

__device__ __forceinline__ float sigm(float a, float b) {
    // softmax over 2 channels, channel 1: 1/(1+exp(a-b)); fp32 fast path
    float z = (a - b) * 1.44269504088896f;          // log2(e)
    float e = __builtin_amdgcn_exp2f(z);            // v_exp_f32
    return __builtin_amdgcn_rcpf(1.0f + e);         // v_rcp_f32
}

// Kernel A: per-row prefix sum of sigmoid(seg1-seg0), fp32 out. One block per row.
// Block 0 also zero-inits the stats accumulators.
__global__ void row_scan(const float* __restrict__ seg, float* __restrict__ rowpref,
                         double* __restrict__ stats) {
    if (blockIdx.x == 0 && threadIdx.x < 5) stats[threadIdx.x] = 0.0;
    const int h = blockIdx.x;
    const int t = threadIdx.x;
    const float4* s0 = (const float4*)(seg + (size_t)h * WW);
    const float4* s1 = (const float4*)(seg + (size_t)(HH * WW) + (size_t)h * WW);
    float4 a = s0[t];
    float4 b = s1[t];
    float p0 = sigm(a.x, b.x);
    float p1 = p0 + sigm(a.y, b.y);
    float p2 = p1 + sigm(a.z, b.z);
    float p3 = p2 + sigm(a.w, b.w);

    // fp32 inclusive scan of per-thread totals across the block
    float tsum = p3;
    const int lane = t & 63, wid = t >> 6;
    #pragma unroll
    for (int off = 1; off < 64; off <<= 1) {
        float n = __shfl_up(tsum, off, 64);
        if (lane >= off) tsum += n;
    }
    __shared__ float wsum[4];
    if (lane == 63) wsum[wid] = tsum;
    __syncthreads();
    float woff = 0.0f;
    for (int k = 0; k < wid; ++k) woff += wsum[k];
    const float excl = woff + tsum - p3;

    float4 o;
    o.x = excl + p0;
    o.y = excl + p1;
    o.z = excl + p2;
    o.w = excl + p3;
    ((float4*)(rowpref + (size_t)h * WW))[t] = o;
}

// Kernel B: per-(16-row chunk, column) partial sums (fp64 acc of fp32). grid (4, 64).
__global__ void col_partial(const float* __restrict__ rowpref, double* __restrict__ bsum) {
    const int w = blockIdx.x * 256 + threadIdx.x;
    const int chunk = blockIdx.y;
    const int r0 = chunk * 16;
    double acc = 0.0;
    #pragma unroll
    for (int r = r0; r < r0 + 16; ++r) acc += (double)rowpref[(size_t)r * WW + w];
    bsum[chunk * WW + w] = acc;
}

// Kernel C: column scan; writes the fp64 integral image C. grid (4, 64).
__global__ void col_scan(const float* __restrict__ rowpref, const double* __restrict__ bsum,
                         double* __restrict__ C) {
    const int w = blockIdx.x * 256 + threadIdx.x;
    const int chunk = blockIdx.y;
    double acc = 0.0;
    for (int k = 0; k < chunk; ++k) acc += bsum[k * WW + w];
    const int r0 = chunk * 16;
    #pragma unroll
    for (int r = r0; r < r0 + 16; ++r) {
        acc += (double)rowpref[(size_t)r * WW + w];
        C[(size_t)r * WW + w] = acc;
    }
}

// Kernel D: per-box iou + fp64 reductions of {Σu, Σu², Σs, Σs²}.
__global__ void box_stats(const int* __restrict__ ssw, const double* __restrict__ C,
                          const float* __restrict__ score,
                          float* __restrict__ iou, double* __restrict__ stats) {
    const int r = blockIdx.x * 256 + threadIdx.x;
    const int* b = ssw + r * 5;
    const int x1 = b[1], y1 = b[2], x2 = b[3], y2 = b[4];
    double p22 = C[(size_t)(y2 - 1) * WW + (x2 - 1)];
    double p12 = (y1 > 0) ? C[(size_t)(y1 - 1) * WW + (x2 - 1)] : 0.0;
    double p21 = (x1 > 0) ? C[(size_t)(y2 - 1) * WW + (x1 - 1)] : 0.0;
    double p11 = (y1 > 0 && x1 > 0) ? C[(size_t)(y1 - 1) * WW + (x1 - 1)] : 0.0;
    double sums = p22 - p12 - p21 + p11;
    double area = (double)((y2 - y1) * (x2 - x1));
    double u = sums / area;
    iou[r] = (float)u;
    double s = (double)score[r];

    double v0 = u, v1 = u * u, v2 = s, v3 = s * s;
    #pragma unroll
    for (int off = 32; off; off >>= 1) {
        v0 += __shfl_down(v0, off, 64);
        v1 += __shfl_down(v1, off, 64);
        v2 += __shfl_down(v2, off, 64);
        v3 += __shfl_down(v3, off, 64);
    }
    if ((threadIdx.x & 63) == 0) {
        atomicAdd(&stats[0], v0);
        atomicAdd(&stats[1], v1);
        atomicAdd(&stats[2], v2);
        atomicAdd(&stats[3], v3);
    }
}

// Kernel E: S_ab = Σ_ij |du|·|ds|  (≈ Σ sqrt((du²+ε)(ds²+ε)), error < 1e-7 in loss).
// Grid (8192/1024, 8192/128) = (8, 64) = 512 blocks, block 256, 4 i per thread.
#define KI 4
#define JT 128
__global__ void pair_prod(const float* __restrict__ iou, const float* __restrict__ score,
                          double* __restrict__ stats) {
    __shared__ float ju[JT];
    __shared__ float js[JT];
    const int t = threadIdx.x;
    const int j0 = blockIdx.y * JT;
    if (t < JT) ju[t] = iou[j0 + t];
    else js[t - JT] = score[j0 + t - JT];

    const int i0 = blockIdx.x * (256 * KI) + t;
    float iu[KI], isc[KI];
    #pragma unroll
    for (int k = 0; k < KI; ++k) {
        iu[k]  = iou[i0 + 256 * k];
        isc[k] = score[i0 + 256 * k];
    }
    __syncthreads();

    float acc[KI];
    #pragma unroll
    for (int k = 0; k < KI; ++k) acc[k] = 0.0f;
    #pragma unroll 8
    for (int j = 0; j < JT; ++j) {
        const float uj = ju[j];
        const float sj = js[j];
        #pragma unroll
        for (int k = 0; k < KI; ++k) {
            float du = iu[k] - uj;
            float ds = isc[k] - sj;
            acc[k] += fabsf(du * ds);   // v_mul + v_add with |src| modifier
        }
    }
    float afl = (acc[0] + acc[1]) + (acc[2] + acc[3]);
    double v = (double)afl;
    #pragma unroll
    for (int off = 32; off; off >>= 1) v += __shfl_down(v, off, 64);
    __shared__ double wred[4];
    const int lane = t & 63, wid = t >> 6;
    if (lane == 0) wred[wid] = v;
    __syncthreads();
    if (t == 0) atomicAdd(&stats[4], wred[0] + wred[1] + wred[2] + wred[3]);
}

// Kernel F: loss = [2RΣu² − 2(Σu)² + 2RΣs² − 2(Σs)² + 2R²ε − 2 S_ab] / R²
__global__ void finalize(const double* __restrict__ stats, float* __restrict__ out) {
    const double R = (double)RR;
    double Su = stats[0], Su2 = stats[1], Ss = stats[2], Ss2 = stats[3], Sab = stats[4];
    double lossR2 = 2.0 * R * Su2 - 2.0 * Su * Su
                  + 2.0 * R * Ss2 - 2.0 * Ss * Ss
                  + 2.0 * R * R * EPSD
                  - 2.0 * Sab;
    out[0] = (float)(lossR2 / (R * R));
}

extern "C" void kernel_launch(void* const* d_in, const int* in_sizes, int n_in,
                              void* d_out, int out_size, void* d_ws, size_t ws_size,
                              hipStream_t stream) {
    const int*   ssw   = (const int*)d_in[0];
    const float* seg   = (const float*)d_in[1];
    const float* score = (const float*)d_in[2];

    float*  rowpref = (float*)d_ws;
    double* C       = (double*)((char*)d_ws + OFF_C);
    double* bsum    = (double*)((char*)d_ws + OFF_BSUM);
    float*  iou     = (float*)((char*)d_ws + OFF_IOU);
    double* stats   = (double*)((char*)d_ws + OFF_STAT);

    row_scan<<<HH, 256, 0, stream>>>(seg, rowpref, stats);
    col_partial<<<dim3(4, 64), 256, 0, stream>>>(rowpref, bsum);
    col_scan<<<dim3(4, 64), 256, 0, stream>>>(rowpref, bsum, C);
    box_stats<<<RR / 256, 256, 0, stream>>>(ssw, C, score, iou, stats);
    pair_prod<<<dim3(RR / (256 * KI), RR / JT), 256, 0, stream>>>(iou, score, stats);
    finalize<<<1, 1, 0, stream>>>(stats, (float*)d_out);
}